// Round 6
// baseline (250.203 us; speedup 1.0000x reference)
//
#include <hip/hip_runtime.h>

// TTN Conv: out[n,p,o,site] = sum_{c,i,j,k,l} a_i b_j c_k d_l * W[c,p,site,ijkl,o] + bias
// Per site: GEMM D[n=128][po=48] = sum_k A[n][k=768] * W[k][po], bf16 MFMA 16x16x32.
//
// x:       (128, 3, 4, 32, 32) fp32
// tensors: (3, 8, 31, 31, 256, 6) fp32  -> per (c,p,site): [m=256][o=6] contiguous
// bias:    (8, 31, 31, 6) fp32
// out:     (128, 8, 6, 31, 31) fp32 = out[f*961 + site], f = n*48 + p*6 + o
//
// R8 = R7 (clean R0 structure + lgkm-only fused barriers) + ONE change:
// W is batch-loaded per c-PANEL (12 float4 = 6 KB per (p,site), all 4 mb
// triples at once) instead of per-chunk 1.5 KB prefetch.
// Rationale: R7 proved barrier/vmcnt scheduling is NOT the bottleneck
// (neutral). Per-chunk mb-sliced loads make the chip-wide HBM pattern a
// read-1.5KB/skip-4.6KB stride over the 142 MB tensor (row-buffer hostile,
// ~30% DRAM eff) -> ~15k-cycle W service per chunk = the observed 84us.
// Batched panel loads stream whole contiguous (c,p) panels chip-wide.
// Consumption is triple-by-triple over the 4 chunks of the c (constant
// wv[] indices under the fully-unrolled ch loop -> register-promoted, same
// mechanism as areg[]/cdreg[] which are proven clean in this kernel).
// Order: x loads first, W second; stage sA (waits x only) before sW (waits
// its W triple) -- later triples stay in flight across the lgkm-only
// barriers (this is where R7's barrier becomes load-bearing).
//
// Phase 1 (1 block/site, 256 thr = 4 waves): K in 12 chunks of 64 (c x mb).
//   sA[128][64] bf16 (stride 72): A[n][ij4*16+kl] = a_mb*b_j * c_k*d_l, from regs.
//   sW[48][64] bf16 (stride 72):  sW[p*6+o][m] transposed from global, b32 writes.
//   Wave w: n in [w*32,w*32+32), 2x3 MFMA tiles.
// Phase 2: tiled transpose ws(961 x 6144) -> out(6144 x 961) + bias.
//
// Canaries: WRITE_SIZE ~23.6 MB (scratch detector), VGPR <= 128.

typedef __attribute__((ext_vector_type(8))) short short8;
typedef __attribute__((ext_vector_type(4))) float floatx4;
typedef __attribute__((ext_vector_type(4))) unsigned int uintx4;

#define WS_ELEMS (961u * 6144u)
#define SA_STR 72
#define SW_STR 72

static __device__ __forceinline__ unsigned short f2bf(float f) {
  union { float f; unsigned u; } v; v.f = f;
  unsigned r = v.u + 0x7FFFu + ((v.u >> 16) & 1u);   // RNE to bf16
  return (unsigned short)(r >> 16);
}

// lgkm drain + workgroup barrier as ONE volatile asm with memory clobber:
// compiler may not move any memory op across it; vmcnt left untouched so
// global loads (W panel triples 1..3) stay in flight across barriers.
static __device__ __forceinline__ void barrier_lgkm() {
  asm volatile("s_waitcnt lgkmcnt(0)\n\ts_barrier" ::: "memory");
  __builtin_amdgcn_sched_barrier(0);
}

template <bool TO_WS>
__global__ __launch_bounds__(256, 4)
void ttn_conv_mfma(const float* __restrict__ x,
                   const float* __restrict__ tensors,
                   const float* __restrict__ bias,
                   float* __restrict__ dst) {
  __shared__ __align__(16) unsigned short sA[128 * SA_STR];  // 18432 B
  __shared__ __align__(16) unsigned short sW[48 * SW_STR];   //  6912 B

  const int site = blockIdx.x;
  const int xx = site / 31, yy = site - xx * 31;
  const int t = threadIdx.x;
  const int lane = t & 63, wave = t >> 6;
  const int row = lane & 15, quad = lane >> 4;

  const int n_st = t & 127;   // sA staging: this thread's n
  const int h = t >> 7;       // sA staging: ij4 in {2h, 2h+1}  (j = 2h+e, i = mb)
  const int p_st = t >> 5;    // sW staging: p (0..7)
  const int q_st = t & 31;    // sW staging: m-pair index (m = 2q, 2q+1)

  floatx4 acc[2][3];
#pragma unroll
  for (int i0 = 0; i0 < 2; ++i0)
#pragma unroll
    for (int j0 = 0; j0 < 3; ++j0)
      acc[i0][j0] = (floatx4){0.f, 0.f, 0.f, 0.f};

  float areg[4], b0 = 0.f, b1 = 0.f, cdreg[16];
  // Full c-panel W slice for this thread: 4 mb triples x 3 float4 (48 regs).
  // Constant-indexed under the fully unrolled ch loop -> register-promoted.
  float4 wv[12];

#pragma unroll
  for (int ch = 0; ch < 12; ++ch) {
    const int mb = ch & 3;
    if ((ch & 3) == 0) {
      const int c = ch >> 2;
      // ---- x factors for this c (issued first; consumed by VALU below) ----
      const float* xp = x + ((size_t)n_st * 3 + c) * 4096 + xx * 32 + yy;
      float bq[4], cq[4], dq[4];
#pragma unroll
      for (int i = 0; i < 4; ++i) {
        const float* r0 = xp + i * 1024;
        areg[i] = r0[0];   // a_i = x[n,c,i,xx,  yy  ]
        cq[i]   = r0[1];   // c_i = x[n,c,i,xx,  yy+1]
        bq[i]   = r0[32];  // b_i = x[n,c,i,xx+1,yy  ]
        dq[i]   = r0[33];  // d_i = x[n,c,i,xx+1,yy+1]
      }
      // ---- batch-load ALL of this c's W: 4 x 48B at 1536B stride ----
      // 32-thread group covers the full 6 KB (p,site) run; chip-wide the
      // (c,p) panels stream contiguously (DRAM row locality).
      {
        const float* src =
            tensors + ((size_t)((c * 8 + p_st) * 961 + site)) * 1536 + 12 * q_st;
#pragma unroll
        for (int mb2 = 0; mb2 < 4; ++mb2) {
          wv[3 * mb2 + 0] = *(const float4*)(src + mb2 * 384);
          wv[3 * mb2 + 1] = *(const float4*)(src + mb2 * 384 + 4);
          wv[3 * mb2 + 2] = *(const float4*)(src + mb2 * 384 + 8);
        }
      }
      // factor math (compiler waits on x loads only; W stays in flight)
      b0 = h ? bq[2] : bq[0];
      b1 = h ? bq[3] : bq[1];
#pragma unroll
      for (int k2 = 0; k2 < 4; ++k2)
#pragma unroll
        for (int l2 = 0; l2 < 4; ++l2)
          cdreg[k2 * 4 + l2] = cq[k2] * dq[l2];
    }
    barrier_lgkm();  // prev chunk's frag reads (lgkm) done before overwrite

    // ---- stage sA[n][ij4*16+kl] = (a_mb * b_{2h+e}) * cd[kl]  (x-only dep) ----
#pragma unroll
    for (int e = 0; e < 2; ++e) {
      const float ab = areg[mb] * (e ? b1 : b0);
      unsigned pk[8];
#pragma unroll
      for (int u = 0; u < 8; ++u)
        pk[u] = (unsigned)f2bf(ab * cdreg[2 * u]) |
                ((unsigned)f2bf(ab * cdreg[2 * u + 1]) << 16);
      uintx4* dp = (uintx4*)&sA[n_st * SA_STR + (2 * h + e) * 16];
      uintx4 v0 = {pk[0], pk[1], pk[2], pk[3]};
      uintx4 v1 = {pk[4], pk[5], pk[6], pk[7]};
      dp[0] = v0;
      dp[1] = v1;
    }
    // ---- stage sW[po][m_local] from this chunk's W triple (waits triple mb) ----
    {
      const float4 w0 = wv[3 * mb + 0];
      const float4 w1 = wv[3 * mb + 1];
      const float4 w2 = wv[3 * mb + 2];
      unsigned short* dW = &sW[(p_st * 6) * SW_STR + 2 * q_st];
      // W[2q][o] = w[o], W[2q+1][o] = w[6+o] (12 contiguous floats)
      *(unsigned*)&dW[0 * SW_STR] = (unsigned)f2bf(w0.x) | ((unsigned)f2bf(w1.z) << 16);
      *(unsigned*)&dW[1 * SW_STR] = (unsigned)f2bf(w0.y) | ((unsigned)f2bf(w1.w) << 16);
      *(unsigned*)&dW[2 * SW_STR] = (unsigned)f2bf(w0.z) | ((unsigned)f2bf(w2.x) << 16);
      *(unsigned*)&dW[3 * SW_STR] = (unsigned)f2bf(w0.w) | ((unsigned)f2bf(w2.y) << 16);
      *(unsigned*)&dW[4 * SW_STR] = (unsigned)f2bf(w1.x) | ((unsigned)f2bf(w2.z) << 16);
      *(unsigned*)&dW[5 * SW_STR] = (unsigned)f2bf(w1.y) | ((unsigned)f2bf(w2.w) << 16);
    }
    barrier_lgkm();  // ds_writes visible before frag reads; vmcnt NOT drained

    // ---- MFMA: 2 K-steps of 32, wave tile 2(M) x 3(N) ----
#pragma unroll
    for (int ks = 0; ks < 2; ++ks) {
      const int kof = ks * 32 + quad * 8;
      short8 af[2], bf[3];
#pragma unroll
      for (int mt = 0; mt < 2; ++mt)
        af[mt] = *(const short8*)&sA[(wave * 32 + mt * 16 + row) * SA_STR + kof];
#pragma unroll
      for (int nt = 0; nt < 3; ++nt)
        bf[nt] = *(const short8*)&sW[(nt * 16 + row) * SW_STR + kof];
#pragma unroll
      for (int mt = 0; mt < 2; ++mt)
#pragma unroll
        for (int nt = 0; nt < 3; ++nt)
          acc[mt][nt] = __builtin_amdgcn_mfma_f32_16x16x32_bf16(
              af[mt], bf[nt], acc[mt][nt], 0, 0, 0);
    }
  }

  // ---- epilogue: D row = quad*4+r (n-local), col = lane&15 (po-local) ----
  if (TO_WS) {
#pragma unroll
    for (int mt = 0; mt < 2; ++mt)
#pragma unroll
      for (int r = 0; r < 4; ++r) {
        const int n = wave * 32 + mt * 16 + quad * 4 + r;
#pragma unroll
        for (int nt = 0; nt < 3; ++nt) {
          const int po = nt * 16 + row;
          dst[(size_t)site * 6144 + n * 48 + po] = acc[mt][nt][r];
        }
      }
  } else {
#pragma unroll
    for (int mt = 0; mt < 2; ++mt)
#pragma unroll
      for (int r = 0; r < 4; ++r) {
        const int n = wave * 32 + mt * 16 + quad * 4 + r;
#pragma unroll
        for (int nt = 0; nt < 3; ++nt) {
          const int po = nt * 16 + row;
          const int p = po / 6, o = po - p * 6;
          dst[(size_t)(n * 48 + po) * 961 + site] =
              acc[mt][nt][r] + bias[(p * 961 + site) * 6 + o];
        }
      }
  }
}

// out[f*961 + site] = ws[site*6144 + f] + bias[(p*961+site)*6 + o],  f = n*48+p*6+o
__global__ __launch_bounds__(256, 8)
void ttn_transpose_bias(const float* __restrict__ ws,
                        const float* __restrict__ bias,
                        float* __restrict__ out) {
  __shared__ float tile[32][33];
  const int f0 = blockIdx.x * 32;
  const int s0 = blockIdx.y * 32;
  const int tx = threadIdx.x;       // 0..31
  const int ty = threadIdx.y;       // 0..7

#pragma unroll
  for (int rr = 0; rr < 4; ++rr) {
    const int srow = ty + rr * 8;
    const int site = s0 + srow;
    if (site < 961)
      tile[srow][tx] = ws[(size_t)site * 6144 + f0 + tx];
  }
  __syncthreads();

#pragma unroll
  for (int rr = 0; rr < 4; ++rr) {
    const int fy = ty + rr * 8;
    const int f = f0 + fy;
    const int site = s0 + tx;
    if (site < 961) {
      const int po = f % 48;
      const int p = po / 6, o = po - p * 6;
      out[(size_t)f * 961 + site] = tile[tx][fy] + bias[(p * 961 + site) * 6 + o];
    }
  }
}

extern "C" void kernel_launch(void* const* d_in, const int* in_sizes, int n_in,
                              void* d_out, int out_size, void* d_ws, size_t ws_size,
                              hipStream_t stream) {
  const float* x       = (const float*)d_in[0];
  const float* tensors = (const float*)d_in[1];
  const float* bias    = (const float*)d_in[2];
  float* out           = (float*)d_out;

  const size_t need = (size_t)WS_ELEMS * sizeof(float);
  if (d_ws != nullptr && ws_size >= need) {
    float* ws = (float*)d_ws;
    hipLaunchKernelGGL((ttn_conv_mfma<true>), dim3(961), dim3(256), 0, stream,
                       x, tensors, bias, ws);
    hipLaunchKernelGGL(ttn_transpose_bias, dim3(192, 31), dim3(32, 8), 0, stream,
                       ws, bias, out);
  } else {
    hipLaunchKernelGGL((ttn_conv_mfma<false>), dim3(961), dim3(256), 0, stream,
                       x, tensors, bias, out);
  }
}

// Round 7
// 244.573 us; speedup vs baseline: 1.0230x; 1.0230x over previous
//
#include <hip/hip_runtime.h>

// TTN Conv: out[n,p,o,site] = sum_{c,i,j,k,l} a_i b_j c_k d_l * W[c,p,site,ijkl,o] + bias
// Per site: GEMM D[n=128][po=48] = sum_k A[n][k=768] * W[k][po], bf16 MFMA 16x16x32.
//
// x:       (128, 3, 4, 32, 32) fp32
// tensors: (3, 8, 31, 31, 256, 6) fp32  -> per (c,p,site): [m=256][o=6] contiguous
// bias:    (8, 31, 31, 6) fp32
// out:     (128, 8, 6, 31, 31) fp32 = out[f*961 + site], f = n*48 + p*6 + o
//
// R9: break the 2-phase convoy. R0/R7/R8 all sit at 85us with every pipe <30%
// busy -- per-chunk serial path = stage + barrier + compute + barrier, 12x,
// with SINGLE-buffered sA/sW forcing the sum. This round: double-buffer BOTH
// sA and sW (50.7 KB LDS, 3 blocks/CU), ONE lgkm-only fused barrier per chunk,
// body = { stage chunk ch+1 into buf^1  ||  MFMA chunk ch from buf }.
// x raw for next c prefetched 3 chunks early (regs); W panel reloaded at
// ch%4==2 (old panel dead). launch_bounds(256,3): VGPR cap ~168 for ~135 live.
// Race audit: body ch writes buf[(ch+1)&1], reads buf[ch&1] (disjoint); reads
// of chunk ch complete (lgkmcnt(0)) at barrier(ch+1) before any wave stages
// chunk ch+2 into that buffer. Staging math byte-identical to R0 (proven).
//
// Phase 2: tiled transpose ws(961 x 6144) -> out(6144 x 961) + bias.
// Canaries: WRITE_SIZE ~23.6 MB (scratch detector), VGPR <= 168, LDS ~50.7 KB.

typedef __attribute__((ext_vector_type(8))) short short8;
typedef __attribute__((ext_vector_type(4))) float floatx4;
typedef __attribute__((ext_vector_type(4))) unsigned int uintx4;

#define WS_ELEMS (961u * 6144u)
#define SA_STR 72
#define SW_STR 72

static __device__ __forceinline__ unsigned short f2bf(float f) {
  union { float f; unsigned u; } v; v.f = f;
  unsigned r = v.u + 0x7FFFu + ((v.u >> 16) & 1u);   // RNE to bf16
  return (unsigned short)(r >> 16);
}

// lgkm drain + workgroup barrier as ONE volatile asm with memory clobber:
// compiler may not move any memory op across it; vmcnt left untouched so
// global loads (x prefetch, W panel) stay in flight across barriers.
static __device__ __forceinline__ void barrier_lgkm() {
  asm volatile("s_waitcnt lgkmcnt(0)\n\ts_barrier" ::: "memory");
  __builtin_amdgcn_sched_barrier(0);
}

template <bool TO_WS>
__global__ __launch_bounds__(256, 3)
void ttn_conv_mfma(const float* __restrict__ x,
                   const float* __restrict__ tensors,
                   const float* __restrict__ bias,
                   float* __restrict__ dst) {
  __shared__ __align__(16) unsigned short sA[2][128 * SA_STR];  // 2 x 18432 B
  __shared__ __align__(16) unsigned short sW[2][48 * SW_STR];   // 2 x  6912 B

  const int site = blockIdx.x;
  const int xx = site / 31, yy = site - xx * 31;
  const int t = threadIdx.x;
  const int lane = t & 63, wave = t >> 6;
  const int row = lane & 15, quad = lane >> 4;

  const int n_st = t & 127;   // sA staging: this thread's n
  const int h = t >> 7;       // sA staging: ij4 in {2h, 2h+1}  (j = 2h+e, i = mb)
  const int p_st = t >> 5;    // sW staging: p (0..7)
  const int q_st = t & 31;    // sW staging: m-pair index (m = 2q, 2q+1)

  floatx4 acc[2][3];
#pragma unroll
  for (int i0 = 0; i0 < 2; ++i0)
#pragma unroll
    for (int j0 = 0; j0 < 3; ++j0)
      acc[i0][j0] = (floatx4){0.f, 0.f, 0.f, 0.f};

  float areg[4], b0 = 0.f, b1 = 0.f, cdreg[16];  // current-c factors
  float nxa[4], nxb[4], nxc[4], nxd[4];          // next-c raw x (prefetch)
  float4 wv[12];                                 // current W panel (c), 4 triples

  const float* xbase = x + (size_t)n_st * 3 * 4096 + xx * 32 + yy;
  const float* wsite = tensors + ((size_t)(p_st * 961 + site)) * 1536 + 12 * q_st;

  // ---- prologue: x(c0) -> factors ----
  {
    float bq[4], cq[4], dq[4];
#pragma unroll
    for (int i = 0; i < 4; ++i) {
      const float* r0 = xbase + i * 1024;
      areg[i] = r0[0];   // a_i = x[n,0,i,xx,  yy  ]
      cq[i]   = r0[1];   // c_i = x[n,0,i,xx,  yy+1]
      bq[i]   = r0[32];  // b_i = x[n,0,i,xx+1,yy  ]
      dq[i]   = r0[33];  // d_i = x[n,0,i,xx+1,yy+1]
    }
    b0 = h ? bq[2] : bq[0];
    b1 = h ? bq[3] : bq[1];
#pragma unroll
    for (int k2 = 0; k2 < 4; ++k2)
#pragma unroll
      for (int l2 = 0; l2 < 4; ++l2)
        cdreg[k2 * 4 + l2] = cq[k2] * dq[l2];
  }
  // ---- prologue: W panel c0 (4 triples, contiguous 6 KB run per (p,site)) ----
#pragma unroll
  for (int mb2 = 0; mb2 < 4; ++mb2) {
    wv[3 * mb2 + 0] = *(const float4*)(wsite + mb2 * 384);
    wv[3 * mb2 + 1] = *(const float4*)(wsite + mb2 * 384 + 4);
    wv[3 * mb2 + 2] = *(const float4*)(wsite + mb2 * 384 + 8);
  }
  // ---- prologue: stage chunk 0 into buf 0 ----
  {
#pragma unroll
    for (int e = 0; e < 2; ++e) {
      const float ab = areg[0] * (e ? b1 : b0);
      unsigned pk[8];
#pragma unroll
      for (int u = 0; u < 8; ++u)
        pk[u] = (unsigned)f2bf(ab * cdreg[2 * u]) |
                ((unsigned)f2bf(ab * cdreg[2 * u + 1]) << 16);
      uintx4* dp = (uintx4*)&sA[0][n_st * SA_STR + (2 * h + e) * 16];
      uintx4 v0 = {pk[0], pk[1], pk[2], pk[3]};
      uintx4 v1 = {pk[4], pk[5], pk[6], pk[7]};
      dp[0] = v0;
      dp[1] = v1;
    }
    const float4 w0 = wv[0], w1 = wv[1], w2 = wv[2];
    unsigned short* dW = &sW[0][(p_st * 6) * SW_STR + 2 * q_st];
    *(unsigned*)&dW[0 * SW_STR] = (unsigned)f2bf(w0.x) | ((unsigned)f2bf(w1.z) << 16);
    *(unsigned*)&dW[1 * SW_STR] = (unsigned)f2bf(w0.y) | ((unsigned)f2bf(w1.w) << 16);
    *(unsigned*)&dW[2 * SW_STR] = (unsigned)f2bf(w0.z) | ((unsigned)f2bf(w2.x) << 16);
    *(unsigned*)&dW[3 * SW_STR] = (unsigned)f2bf(w0.w) | ((unsigned)f2bf(w2.y) << 16);
    *(unsigned*)&dW[4 * SW_STR] = (unsigned)f2bf(w1.x) | ((unsigned)f2bf(w2.z) << 16);
    *(unsigned*)&dW[5 * SW_STR] = (unsigned)f2bf(w1.y) | ((unsigned)f2bf(w2.w) << 16);
  }

#pragma unroll
  for (int ch = 0; ch < 12; ++ch) {
    barrier_lgkm();  // chunk ch staged & visible; prev reads drained

    // (A) issue next-c x raw loads (3 chunks of latency cover)
    if ((ch & 3) == 0 && (ch >> 2) < 2) {
      const int cn = (ch >> 2) + 1;
      const float* xp = xbase + cn * 4096;
#pragma unroll
      for (int i = 0; i < 4; ++i) {
        const float* r0 = xp + i * 1024;
        nxa[i] = r0[0];
        nxc[i] = r0[1];
        nxb[i] = r0[32];
        nxd[i] = r0[33];
      }
    }
    // (B) at c-boundary: build next-c factors (old factors dead since ch%4==2)
    if ((ch & 3) == 3 && (ch >> 2) < 2) {
#pragma unroll
      for (int i = 0; i < 4; ++i) areg[i] = nxa[i];
      b0 = h ? nxb[2] : nxb[0];
      b1 = h ? nxb[3] : nxb[1];
#pragma unroll
      for (int k2 = 0; k2 < 4; ++k2)
#pragma unroll
        for (int l2 = 0; l2 < 4; ++l2)
          cdreg[k2 * 4 + l2] = nxc[k2] * nxd[l2];
    }
    // (C) stage chunk ch+1 into buf[(ch+1)&1]  (overlaps (E) below)
    if (ch < 11) {
      const int mb1 = (ch + 1) & 3;
      const int bs = (ch + 1) & 1;
#pragma unroll
      for (int e = 0; e < 2; ++e) {
        const float ab = areg[mb1] * (e ? b1 : b0);
        unsigned pk[8];
#pragma unroll
        for (int u = 0; u < 8; ++u)
          pk[u] = (unsigned)f2bf(ab * cdreg[2 * u]) |
                  ((unsigned)f2bf(ab * cdreg[2 * u + 1]) << 16);
        uintx4* dp = (uintx4*)&sA[bs][n_st * SA_STR + (2 * h + e) * 16];
        uintx4 v0 = {pk[0], pk[1], pk[2], pk[3]};
        uintx4 v1 = {pk[4], pk[5], pk[6], pk[7]};
        dp[0] = v0;
        dp[1] = v1;
      }
      const float4 w0 = wv[3 * mb1 + 0];
      const float4 w1 = wv[3 * mb1 + 1];
      const float4 w2 = wv[3 * mb1 + 2];
      unsigned short* dW = &sW[bs][(p_st * 6) * SW_STR + 2 * q_st];
      *(unsigned*)&dW[0 * SW_STR] = (unsigned)f2bf(w0.x) | ((unsigned)f2bf(w1.z) << 16);
      *(unsigned*)&dW[1 * SW_STR] = (unsigned)f2bf(w0.y) | ((unsigned)f2bf(w1.w) << 16);
      *(unsigned*)&dW[2 * SW_STR] = (unsigned)f2bf(w0.z) | ((unsigned)f2bf(w2.x) << 16);
      *(unsigned*)&dW[3 * SW_STR] = (unsigned)f2bf(w0.w) | ((unsigned)f2bf(w2.y) << 16);
      *(unsigned*)&dW[4 * SW_STR] = (unsigned)f2bf(w1.x) | ((unsigned)f2bf(w2.z) << 16);
      *(unsigned*)&dW[5 * SW_STR] = (unsigned)f2bf(w1.y) | ((unsigned)f2bf(w2.w) << 16);
    }
    // (D) reload W panel for next c (current panel fully consumed by (C) above)
    if ((ch & 3) == 2 && (ch >> 2) < 2) {
      const int cn = (ch >> 2) + 1;
      const float* src = wsite + (size_t)cn * 8 * 961 * 1536;
#pragma unroll
      for (int mb2 = 0; mb2 < 4; ++mb2) {
        wv[3 * mb2 + 0] = *(const float4*)(src + mb2 * 384);
        wv[3 * mb2 + 1] = *(const float4*)(src + mb2 * 384 + 4);
        wv[3 * mb2 + 2] = *(const float4*)(src + mb2 * 384 + 8);
      }
    }

    // (E) MFMA chunk ch from buf[ch&1]: 2 K-steps of 32, wave tile 2(M) x 3(N)
#pragma unroll
    for (int ks = 0; ks < 2; ++ks) {
      const int kof = ks * 32 + quad * 8;
      short8 af[2], bf[3];
#pragma unroll
      for (int mt = 0; mt < 2; ++mt)
        af[mt] = *(const short8*)&sA[ch & 1][(wave * 32 + mt * 16 + row) * SA_STR + kof];
#pragma unroll
      for (int nt = 0; nt < 3; ++nt)
        bf[nt] = *(const short8*)&sW[ch & 1][(nt * 16 + row) * SW_STR + kof];
#pragma unroll
      for (int mt = 0; mt < 2; ++mt)
#pragma unroll
        for (int nt = 0; nt < 3; ++nt)
          acc[mt][nt] = __builtin_amdgcn_mfma_f32_16x16x32_bf16(
              af[mt], bf[nt], acc[mt][nt], 0, 0, 0);
    }
  }

  // ---- epilogue: D row = quad*4+r (n-local), col = lane&15 (po-local) ----
  if (TO_WS) {
#pragma unroll
    for (int mt = 0; mt < 2; ++mt)
#pragma unroll
      for (int r = 0; r < 4; ++r) {
        const int n = wave * 32 + mt * 16 + quad * 4 + r;
#pragma unroll
        for (int nt = 0; nt < 3; ++nt) {
          const int po = nt * 16 + row;
          dst[(size_t)site * 6144 + n * 48 + po] = acc[mt][nt][r];
        }
      }
  } else {
#pragma unroll
    for (int mt = 0; mt < 2; ++mt)
#pragma unroll
      for (int r = 0; r < 4; ++r) {
        const int n = wave * 32 + mt * 16 + quad * 4 + r;
#pragma unroll
        for (int nt = 0; nt < 3; ++nt) {
          const int po = nt * 16 + row;
          const int p = po / 6, o = po - p * 6;
          dst[(size_t)(n * 48 + po) * 961 + site] =
              acc[mt][nt][r] + bias[(p * 961 + site) * 6 + o];
        }
      }
  }
}

// out[f*961 + site] = ws[site*6144 + f] + bias[(p*961+site)*6 + o],  f = n*48+p*6+o
__global__ __launch_bounds__(256, 8)
void ttn_transpose_bias(const float* __restrict__ ws,
                        const float* __restrict__ bias,
                        float* __restrict__ out) {
  __shared__ float tile[32][33];
  const int f0 = blockIdx.x * 32;
  const int s0 = blockIdx.y * 32;
  const int tx = threadIdx.x;       // 0..31
  const int ty = threadIdx.y;       // 0..7

#pragma unroll
  for (int rr = 0; rr < 4; ++rr) {
    const int srow = ty + rr * 8;
    const int site = s0 + srow;
    if (site < 961)
      tile[srow][tx] = ws[(size_t)site * 6144 + f0 + tx];
  }
  __syncthreads();

#pragma unroll
  for (int rr = 0; rr < 4; ++rr) {
    const int fy = ty + rr * 8;
    const int f = f0 + fy;
    const int site = s0 + tx;
    if (site < 961) {
      const int po = f % 48;
      const int p = po / 6, o = po - p * 6;
      out[(size_t)f * 961 + site] = tile[tx][fy] + bias[(p * 961 + site) * 6 + o];
    }
  }
}

extern "C" void kernel_launch(void* const* d_in, const int* in_sizes, int n_in,
                              void* d_out, int out_size, void* d_ws, size_t ws_size,
                              hipStream_t stream) {
  const float* x       = (const float*)d_in[0];
  const float* tensors = (const float*)d_in[1];
  const float* bias    = (const float*)d_in[2];
  float* out           = (float*)d_out;

  const size_t need = (size_t)WS_ELEMS * sizeof(float);
  if (d_ws != nullptr && ws_size >= need) {
    float* ws = (float*)d_ws;
    hipLaunchKernelGGL((ttn_conv_mfma<true>), dim3(961), dim3(256), 0, stream,
                       x, tensors, bias, ws);
    hipLaunchKernelGGL(ttn_transpose_bias, dim3(192, 31), dim3(32, 8), 0, stream,
                       ws, bias, out);
  } else {
    hipLaunchKernelGGL((ttn_conv_mfma<false>), dim3(961), dim3(256), 0, stream,
                       x, tensors, bias, out);
  }
}

// Round 8
// 241.306 us; speedup vs baseline: 1.0369x; 1.0135x over previous
//
#include <hip/hip_runtime.h>

// TTN Conv: out[n,p,o,site] = sum_{c,i,j,k,l} a_i b_j c_k d_l * W[c,p,site,ijkl,o] + bias
// Per site: GEMM D[n=128][po=48] = sum_k A[n][k=768] * W[k][po], bf16 MFMA 16x16x32.
//
// x:       (128, 3, 4, 32, 32) fp32
// tensors: (3, 8, 31, 31, 256, 6) fp32  -> per (c,p,site): [m=256][o=6] contiguous
// bias:    (8, 31, 31, 6) fp32
// out:     (128, 8, 6, 31, 31) fp32 = out[f*961 + site], f = n*48 + p*6 + o
//
// R10 = R7 base (proven clean: WRITE 23.6 MB, VGPR~60, 85us) + ONE change:
// the divergent x gather is DEDUPED + WIDENED through LDS (sX).
// Old: 16 scalar loads/thread/c, 64 distinct lines per wave-instr, 2x thread
// duplication -> 12288 line-requests per block (~20us of serialized L1/TA
// service chip-wide; invariant across R0-R9, all of which were neutral).
// New: 1024 row-tasks per c (n x i x {xx,xx+1}), each ONE float2 (even yy,
// block-uniform branch) or two dwords (odd yy); 4 tasks/thread -> raw into
// sX[128][20] floats; factors built from 4x ds_read_b128/thread at c-bounds.
// Requests per block: 12288 -> ~3-6k. sX single-buffered: writes at ch%4==1
// (for c+1), reads at ch%4==0 -- >=2 barriers separation each way.
// LDS 18432(sA) + 6912(sW) + 10240(sX) = 35584 B -> still 4 blocks/CU.
//
// Phase 1 (1 block/site, 256 thr): K in 12 chunks of 64 (c x mb).
//   sA[128][64] bf16 (str 72), sW[48][64] bf16 (str 72), W 1-chunk prefetch,
//   fused lgkm-only barriers (R7). Wave w: n in [w*32,+32), 2x3 MFMA tiles.
// Phase 2: tiled transpose ws(961 x 6144) -> out(6144 x 961) + bias.
// Canaries: WRITE_SIZE ~23.6 MB, VGPR <= 128, LDS_Block ~35.6 KB.

typedef __attribute__((ext_vector_type(8))) short short8;
typedef __attribute__((ext_vector_type(4))) float floatx4;
typedef __attribute__((ext_vector_type(4))) unsigned int uintx4;

#define WS_ELEMS (961u * 6144u)
#define SA_STR 72
#define SW_STR 72
#define SX_STR 20   // floats; 80 B row: 16B-aligned for b128 reads

static __device__ __forceinline__ unsigned short f2bf(float f) {
  union { float f; unsigned u; } v; v.f = f;
  unsigned r = v.u + 0x7FFFu + ((v.u >> 16) & 1u);   // RNE to bf16
  return (unsigned short)(r >> 16);
}

// lgkm drain + workgroup barrier as ONE volatile asm with memory clobber:
// compiler may not move any memory op across it; vmcnt left untouched so
// global loads (W prefetch, x gathers) stay in flight across barriers.
static __device__ __forceinline__ void barrier_lgkm() {
  asm volatile("s_waitcnt lgkmcnt(0)\n\ts_barrier" ::: "memory");
  __builtin_amdgcn_sched_barrier(0);
}

template <bool TO_WS>
__global__ __launch_bounds__(256, 4)
void ttn_conv_mfma(const float* __restrict__ x,
                   const float* __restrict__ tensors,
                   const float* __restrict__ bias,
                   float* __restrict__ dst) {
  __shared__ __align__(16) unsigned short sA[128 * SA_STR];  // 18432 B
  __shared__ __align__(16) unsigned short sW[48 * SW_STR];   //  6912 B
  __shared__ __align__(16) float sX[128 * SX_STR];           // 10240 B

  const int site = blockIdx.x;
  const int xx = site / 31, yy = site - xx * 31;
  const int t = threadIdx.x;
  const int lane = t & 63, wave = t >> 6;
  const int row = lane & 15, quad = lane >> 4;

  const int n_st = t & 127;   // sA staging: this thread's n
  const int h = t >> 7;       // sA staging: ij4 in {2h, 2h+1}  (j = 2h+e, i = mb)
  const int p_st = t >> 5;    // sW staging: p (0..7)
  const int q_st = t & 31;    // sW staging: m-pair index (m = 2q, 2q+1)

  // x-gather task mapping: row-task r = t + 256*s (s=0..3):
  //   n = r>>3, i = (r>>1)&3, half = r&1 (0: row xx -> (a,c); 1: row xx+1 -> (b,d))
  const int gn0 = t >> 3, gi = (t >> 1) & 3, ghalf = t & 1;

  floatx4 acc[2][3];
#pragma unroll
  for (int i0 = 0; i0 < 2; ++i0)
#pragma unroll
    for (int j0 = 0; j0 < 3; ++j0)
      acc[i0][j0] = (floatx4){0.f, 0.f, 0.f, 0.f};

  float areg[4], b0 = 0.f, b1 = 0.f, cdreg[16];
  float4 wv0, wv1, wv2;

  // ---- stage sX for channel c: 4 deduped row-gathers per thread ----
  auto stage_sX = [&](int c) {
#pragma unroll
    for (int s = 0; s < 4; ++s) {
      const int n = gn0 + 32 * s;
      const float* src = x + ((size_t)n * 3 + c) * 4096 + gi * 1024 +
                         (xx + ghalf) * 32 + yy;
      float v0, v1;
      if (yy & 1) {            // block-uniform branch; odd yy: two dwords
        v0 = src[0];
        v1 = src[1];
      } else {                 // even yy: one 8B-aligned float2
        const float2 vv = *(const float2*)src;
        v0 = vv.x;
        v1 = vv.y;
      }
      *(float2*)&sX[n * SX_STR + gi * 4 + ghalf * 2] = float2{v0, v1};
    }
  };

  // ---- build per-thread factors from sX (4 x ds_read_b128) ----
  auto build_factors = [&]() {
    float bq[4], cq[4], dq[4];
#pragma unroll
    for (int i = 0; i < 4; ++i) {
      const float4 v = *(const float4*)&sX[n_st * SX_STR + i * 4];
      areg[i] = v.x;   // a_i = x[n,c,i,xx,  yy  ]
      cq[i]   = v.y;   // c_i = x[n,c,i,xx,  yy+1]
      bq[i]   = v.z;   // b_i = x[n,c,i,xx+1,yy  ]
      dq[i]   = v.w;   // d_i = x[n,c,i,xx+1,yy+1]
    }
    b0 = h ? bq[2] : bq[0];
    b1 = h ? bq[3] : bq[1];
#pragma unroll
    for (int k2 = 0; k2 < 4; ++k2)
#pragma unroll
      for (int l2 = 0; l2 < 4; ++l2)
        cdreg[k2 * 4 + l2] = cq[k2] * dq[l2];
  };

  // ---- prologue: sX(c0) -> factors; W chunk-0 prefetch ----
  stage_sX(0);
  barrier_lgkm();
  build_factors();
  {
    const float* src = tensors + ((size_t)(p_st * 961 + site)) * 1536 + 12 * q_st;
    wv0 = *(const float4*)src;
    wv1 = *(const float4*)(src + 4);
    wv2 = *(const float4*)(src + 8);
  }

#pragma unroll
  for (int ch = 0; ch < 12; ++ch) {
    const int mb = ch & 3;
    // factors for this c (sX written >=3 iterations ago, barrier-separated)
    if (mb == 0 && ch > 0) build_factors();
    // stage sX for next c (reads of current c completed above at ch-1's c-bound;
    // writes drained at this iteration's barrier, read 3 iterations later)
    if (mb == 1 && ch < 9) stage_sX((ch >> 2) + 1);

    barrier_lgkm();  // prev chunk's frag reads (lgkm) done before overwrite

    // ---- stage sW[po][m_local] from prefetched regs (12 floats = m pair x 6 o) ----
    {
      const float vv[12] = {wv0.x, wv0.y, wv0.z, wv0.w, wv1.x, wv1.y,
                            wv1.z, wv1.w, wv2.x, wv2.y, wv2.z, wv2.w};
#pragma unroll
      for (int o = 0; o < 6; ++o) {
        const unsigned pk = (unsigned)f2bf(vv[o]) | ((unsigned)f2bf(vv[o + 6]) << 16);
        *(unsigned*)&sW[(p_st * 6 + o) * SW_STR + 2 * q_st] = pk;
      }
    }
    // ---- stage sA[n][ij4*16+kl] = (a_mb * b_{2h+e}) * cd[kl] ----
#pragma unroll
    for (int e = 0; e < 2; ++e) {
      const float ab = areg[mb] * (e ? b1 : b0);
      unsigned pk[8];
#pragma unroll
      for (int u = 0; u < 8; ++u)
        pk[u] = (unsigned)f2bf(ab * cdreg[2 * u]) |
                ((unsigned)f2bf(ab * cdreg[2 * u + 1]) << 16);
      uintx4* dp = (uintx4*)&sA[n_st * SA_STR + (2 * h + e) * 16];
      uintx4 v0 = {pk[0], pk[1], pk[2], pk[3]};
      uintx4 v1 = {pk[4], pk[5], pk[6], pk[7]};
      dp[0] = v0;
      dp[1] = v1;
    }
    // ---- prefetch next chunk's W (rides across the barrier) ----
    if (ch < 11) {
      const int cn = (ch + 1) >> 2, mbn = (ch + 1) & 3;
      const float* src = tensors +
          ((size_t)((cn * 8 + p_st) * 961 + site)) * 1536 + (mbn * 64 + 2 * q_st) * 6;
      wv0 = *(const float4*)src;
      wv1 = *(const float4*)(src + 4);
      wv2 = *(const float4*)(src + 8);
    }
    barrier_lgkm();  // ds_writes visible before frag reads; vmcnt NOT drained

    // ---- MFMA: 2 K-steps of 32, wave tile 2(M) x 3(N) ----
#pragma unroll
    for (int ks = 0; ks < 2; ++ks) {
      const int kof = ks * 32 + quad * 8;
      short8 af[2], bf[3];
#pragma unroll
      for (int mt = 0; mt < 2; ++mt)
        af[mt] = *(const short8*)&sA[(wave * 32 + mt * 16 + row) * SA_STR + kof];
#pragma unroll
      for (int nt = 0; nt < 3; ++nt)
        bf[nt] = *(const short8*)&sW[(nt * 16 + row) * SW_STR + kof];
#pragma unroll
      for (int mt = 0; mt < 2; ++mt)
#pragma unroll
        for (int nt = 0; nt < 3; ++nt)
          acc[mt][nt] = __builtin_amdgcn_mfma_f32_16x16x32_bf16(
              af[mt], bf[nt], acc[mt][nt], 0, 0, 0);
    }
  }

  // ---- epilogue: D row = quad*4+r (n-local), col = lane&15 (po-local) ----
  if (TO_WS) {
#pragma unroll
    for (int mt = 0; mt < 2; ++mt)
#pragma unroll
      for (int r = 0; r < 4; ++r) {
        const int n = wave * 32 + mt * 16 + quad * 4 + r;
#pragma unroll
        for (int nt = 0; nt < 3; ++nt) {
          const int po = nt * 16 + row;
          dst[(size_t)site * 6144 + n * 48 + po] = acc[mt][nt][r];
        }
      }
  } else {
#pragma unroll
    for (int mt = 0; mt < 2; ++mt)
#pragma unroll
      for (int r = 0; r < 4; ++r) {
        const int n = wave * 32 + mt * 16 + quad * 4 + r;
#pragma unroll
        for (int nt = 0; nt < 3; ++nt) {
          const int po = nt * 16 + row;
          const int p = po / 6, o = po - p * 6;
          dst[(size_t)(n * 48 + po) * 961 + site] =
              acc[mt][nt][r] + bias[(p * 961 + site) * 6 + o];
        }
      }
  }
}

// out[f*961 + site] = ws[site*6144 + f] + bias[(p*961+site)*6 + o],  f = n*48+p*6+o
__global__ __launch_bounds__(256, 8)
void ttn_transpose_bias(const float* __restrict__ ws,
                        const float* __restrict__ bias,
                        float* __restrict__ out) {
  __shared__ float tile[32][33];
  const int f0 = blockIdx.x * 32;
  const int s0 = blockIdx.y * 32;
  const int tx = threadIdx.x;       // 0..31
  const int ty = threadIdx.y;       // 0..7

#pragma unroll
  for (int rr = 0; rr < 4; ++rr) {
    const int srow = ty + rr * 8;
    const int site = s0 + srow;
    if (site < 961)
      tile[srow][tx] = ws[(size_t)site * 6144 + f0 + tx];
  }
  __syncthreads();

#pragma unroll
  for (int rr = 0; rr < 4; ++rr) {
    const int fy = ty + rr * 8;
    const int f = f0 + fy;
    const int site = s0 + tx;
    if (site < 961) {
      const int po = f % 48;
      const int p = po / 6, o = po - p * 6;
      out[(size_t)f * 961 + site] = tile[tx][fy] + bias[(p * 961 + site) * 6 + o];
    }
  }
}

extern "C" void kernel_launch(void* const* d_in, const int* in_sizes, int n_in,
                              void* d_out, int out_size, void* d_ws, size_t ws_size,
                              hipStream_t stream) {
  const float* x       = (const float*)d_in[0];
  const float* tensors = (const float*)d_in[1];
  const float* bias    = (const float*)d_in[2];
  float* out           = (float*)d_out;

  const size_t need = (size_t)WS_ELEMS * sizeof(float);
  if (d_ws != nullptr && ws_size >= need) {
    float* ws = (float*)d_ws;
    hipLaunchKernelGGL((ttn_conv_mfma<true>), dim3(961), dim3(256), 0, stream,
                       x, tensors, bias, ws);
    hipLaunchKernelGGL(ttn_transpose_bias, dim3(192, 31), dim3(32, 8), 0, stream,
                       ws, bias, out);
  } else {
    hipLaunchKernelGGL((ttn_conv_mfma<false>), dim3(961), dim3(256), 0, stream,
                       x, tensors, bias, out);
  }
}